// Round 13
// baseline (162.167 us; speedup 1.0000x reference)
//
#include <hip/hip_runtime.h>
#include <hip/hip_bf16.h>

typedef unsigned int u32;
typedef unsigned short u16;

// Problem constants (from reference)
#define N_NODE 8192
#define H1 512
#define R_EMB 128
#define N_EDGE 262144
#define N_REG 2048

// ---------------- workspace layout (bytes) ----------------
#define OFF_DEG        (0)               // int32 x 8192
#define OFF_ROWSTART   (64 * 1024)       // int32 x 8193
#define OFF_CURSOR     (128 * 1024)      // int32 x 8192
#define OFF_DIS        (160 * 1024)      // f32   x 8192
#define OFF_SORTED     (256 * 1024)      // int32 x 262144 (1 MiB)
#define OFF_W1H        (2 * 1024 * 1024)   // half-major bf16: u32[2][8192][128] (8 MiB), pre-scaled by dis[row]
#define OFF_H1S        (10 * 1024 * 1024)  // row-major bf16:  u32[8192][256] (8 MiB)  h1s = dis*relu(...)
#define OFF_W2T        (18 * 1024 * 1024)  // bf16 pairs: u32[128][256] (128 KiB) W2 transposed
#define OFF_H2B        (19 * 1024 * 1024)  // bf16: u16[8192][128] = u32[8192][64] (2 MiB)  h2 = h1s @ W2

#define HALF_U32 (N_NODE * 128)   // u32 per half-plane (1<<20)

__device__ inline u32 rne_bf16(float f) {
    u32 u = __float_as_uint(f);
    u += 0x7fffu + ((u >> 16) & 1u);
    return u >> 16;
}
__device__ inline float bf_lo(u32 u) { return __uint_as_float(u << 16); }
__device__ inline float bf_hi(u32 u) { return __uint_as_float(u & 0xffff0000u); }

using frag_ab = __attribute__((ext_vector_type(8))) short;  // 8 bf16 (4 VGPRs)
using frag_cd = __attribute__((ext_vector_type(4))) float;  // 4 fp32

// NOTE: macro parameter must not be named 'w'/'x'/'y' (member-token collision)
#define ACC4(v, q) \
    v##0 += bf_lo(q.x); v##1 += bf_hi(q.x); \
    v##2 += bf_lo(q.y); v##3 += bf_hi(q.y);

__global__ void hist_kernel(const int* __restrict__ edge, int* __restrict__ deg) {
    int e = blockIdx.x * blockDim.x + threadIdx.x;
    if (e < N_EDGE) {
        int dst = edge[2 * e + 1];
        atomicAdd(&deg[dst], 1);
    }
}

// 1024 threads: exclusive scan of deg[8192] -> row_start, cursor; dis = rsqrt(deg+1).
__global__ void scan_kernel(const int* __restrict__ deg, int* __restrict__ row_start,
                            int* __restrict__ cursor, float* __restrict__ dis) {
    __shared__ int wtot[16];
    __shared__ int wpre[16];
    int t = threadIdx.x;
    int lane = t & 63;
    int wv = t >> 6;
    int base = t * 8;
    int local[8];
    int sum = 0;
#pragma unroll
    for (int j = 0; j < 8; j++) {
        local[j] = deg[base + j];
        sum += local[j];
    }
    int sc = sum;
#pragma unroll
    for (int off = 1; off < 64; off <<= 1) {
        int y = __shfl_up(sc, off, 64);
        if (lane >= off) sc += y;
    }
    if (lane == 63) wtot[wv] = sc;
    __syncthreads();
    if (wv == 0 && lane < 16) {
        int v = wtot[lane];
        int s2 = v;
#pragma unroll
        for (int off = 1; off < 16; off <<= 1) {
            int y = __shfl_up(s2, off, 64);
            if (lane >= off) s2 += y;
        }
        wpre[lane] = s2 - v;  // exclusive wave prefix
    }
    __syncthreads();
    int run = wpre[wv] + (sc - sum);
#pragma unroll
    for (int j = 0; j < 8; j++) {
        row_start[base + j] = run;
        cursor[base + j] = run;
        dis[base + j] = rsqrtf((float)(local[j] + 1));
        run += local[j];
    }
    if (t == 1023) row_start[N_NODE] = run;
}

// Fused prep:
//   blocks [0,1024):      fill CSR
//   blocks [1024,5120):   W1 -> half-major bf16*dis   W1h[h][row][128 u32]
//   blocks [5120,5248):   W2^T -> bf16
__global__ void prep_kernel(const int* __restrict__ edge, int* __restrict__ cursor,
                            int* __restrict__ sorted_src,
                            const float* __restrict__ W1, const float* __restrict__ dis,
                            u32* __restrict__ W1h,
                            const float* __restrict__ W2, u32* __restrict__ w2t) {
    int bid = blockIdx.x;
    if (bid < 1024) {
        int e = bid * 256 + threadIdx.x;
        int src = edge[2 * e + 0];
        int dst = edge[2 * e + 1];
        int pos = atomicAdd(&cursor[dst], 1);
        sorted_src[pos] = src;
    } else if (bid < 5120) {
        int idx = (bid - 1024) * 256 + threadIdx.x;  // uint2 units
        int j2 = idx & 63;            // uint2 within half-row (4 features)
        int row = (idx >> 6) & 8191;
        int h = idx >> 19;            // 0..1
        float d = dis[row];
        float4 f = *(const float4*)(W1 + ((size_t)row << 9) + (h << 8) + (j2 << 2));
        uint2 o;
        o.x = rne_bf16(f.x * d) | (rne_bf16(f.y * d) << 16);
        o.y = rne_bf16(f.z * d) | (rne_bf16(f.w * d) << 16);
        *(uint2*)(W1h + ((size_t)h * HALF_U32) + (row << 7) + (j2 << 1)) = o;
    } else {
        int idx = (bid - 5120) * 256 + threadIdx.x;  // 0..32767
        int j = idx >> 8;     // output column
        int p = idx & 255;    // k-pair
        float a = W2[(size_t)(2 * p) * R_EMB + j];
        float b = W2[(size_t)(2 * p + 1) * R_EMB + j];
        w2t[idx] = rne_bf16(a) | (rne_bf16(b) << 16);
    }
}

// Layer 1, one feature-HALF per launch (clean L2 phase separation).
// Grid: 2048 blocks x 256 (4 waves), wave per node. Working set = one 4 MiB half-plane.
// Writes h1s ROW-major u32[8192][256] at column offset half*128 (for the MFMA GEMM).
__global__ __launch_bounds__(256) void layer1_phase(const u32* __restrict__ W1h,
                                                    const float* __restrict__ b1,
                                                    const int* __restrict__ row_start,
                                                    const int* __restrict__ sorted_src,
                                                    const float* __restrict__ dis,
                                                    u32* __restrict__ h1s, int half) {
    int d = (blockIdx.x << 2) + (threadIdx.x >> 6);
    int lane = threadIdx.x & 63;
    const u32* basep = W1h + (size_t)half * HALF_U32;
    int loff = lane << 1;
    float disd = dis[d];

    uint2 wd = *(const uint2*)(basep + (d << 7) + loff);
    float a0 = bf_lo(wd.x), a1 = bf_hi(wd.x), a2 = bf_lo(wd.y), a3 = bf_hi(wd.y);
    float c0 = 0, c1 = 0, c2 = 0, c3 = 0;

    int beg = row_start[d], end = row_start[d + 1];
    int i = beg;
    int rem = (end - beg) & 3;
    for (int r = 0; r < rem; r++) {
        int s = sorted_src[i++];
        uint2 v0 = *(const uint2*)(basep + (s << 7) + loff);
        ACC4(a, v0)
    }
    for (; i < end; i += 4) {
        int s0 = sorted_src[i];
        int s1 = sorted_src[i + 1];
        int s2 = sorted_src[i + 2];
        int s3 = sorted_src[i + 3];
        uint2 v0 = *(const uint2*)(basep + (s0 << 7) + loff);
        uint2 v1 = *(const uint2*)(basep + (s1 << 7) + loff);
        uint2 v2 = *(const uint2*)(basep + (s2 << 7) + loff);
        uint2 v3 = *(const uint2*)(basep + (s3 << 7) + loff);
        ACC4(a, v0)
        ACC4(c, v1)
        ACC4(a, v2)
        ACC4(c, v3)
    }
    a0 += c0; a1 += c1; a2 += c2; a3 += c3;

    float4 bb = *(const float4*)(b1 + (half << 8) + (lane << 2));
    float o0 = fmaxf(a0 * disd + bb.x, 0.0f) * disd;
    float o1 = fmaxf(a1 * disd + bb.y, 0.0f) * disd;
    float o2 = fmaxf(a2 * disd + bb.z, 0.0f) * disd;
    float o3 = fmaxf(a3 * disd + bb.w, 0.0f) * disd;
    uint2 o;
    o.x = rne_bf16(o0) | (rne_bf16(o1) << 16);
    o.y = rne_bf16(o2) | (rne_bf16(o3) << 16);
    *(uint2*)(h1s + ((size_t)d << 8) + (half << 7) + loff) = o;
}

// h2 = h1s @ W2 (bf16 MFMA).  M=8192, K=512, N=128 -> h2b bf16 u16[8192][128].
// 4096 tile-waves = 1024 blocks x 4 waves. Same fragment scheme as before.
// D: col = lane&15, row = (lane>>4)*4 + reg  [m89-verified].
__global__ void gemm_h2(const u32* __restrict__ h1s, const u32* __restrict__ w2t_bf,
                        u16* __restrict__ h2b) {
    int w = blockIdx.x * 4 + (threadIdx.x >> 6);   // 0..4095
    int lane = threadIdx.x & 63;
    int tm = w >> 3;        // 0..511
    int tn = w & 7;         // 0..7
    int r15 = lane & 15;
    int kb4 = (lane >> 4) << 2;

    const uint4* arow = (const uint4*)(h1s + ((tm * 16 + r15) << 8) + kb4);
    const uint4* brow = (const uint4*)(w2t_bf + ((tn * 16 + r15) << 8) + kb4);
    frag_cd acc = {0.0f, 0.0f, 0.0f, 0.0f};
#pragma unroll
    for (int kk = 0; kk < 16; kk++) {
        uint4 av = arow[kk * 4];
        uint4 bv = brow[kk * 4];
        acc = __builtin_amdgcn_mfma_f32_16x16x32_bf16(*(frag_ab*)&av, *(frag_ab*)&bv, acc, 0, 0, 0);
    }
    int col = tn * 16 + r15;
    int row0 = tm * 16 + ((lane >> 4) << 2);
#pragma unroll
    for (int r = 0; r < 4; r++)
        h2b[(size_t)(row0 + r) * R_EMB + col] = (u16)rne_bf16(acc[r]);
}

// Layer 2 on h2 (2 MiB, L2-resident): wave per target, lane owns 2 features.
// out[t] = dis[d]*(sum_s h2[s] + h2[d]) + b2,  d = reg_id[t].  fp32 out.
__global__ __launch_bounds__(256) void layer2_small(const u32* __restrict__ h2u,
                                                    const int* __restrict__ reg_id,
                                                    const int* __restrict__ row_start,
                                                    const int* __restrict__ sorted_src,
                                                    const float* __restrict__ dis,
                                                    const float* __restrict__ b2,
                                                    float* __restrict__ out) {
    int tgt = (blockIdx.x << 2) + (threadIdx.x >> 6);
    int lane = threadIdx.x & 63;
    int d = reg_id[tgt];
    float disd = dis[d];

    u32 wd = h2u[(d << 6) + lane];
    float a0 = bf_lo(wd), a1 = bf_hi(wd);
    float c0 = 0, c1 = 0;

    int beg = row_start[d], end = row_start[d + 1];
    int i = beg;
    int rem = (end - beg) & 3;
    for (int r = 0; r < rem; r++) {
        int s = sorted_src[i++];
        u32 v = h2u[(s << 6) + lane];
        a0 += bf_lo(v); a1 += bf_hi(v);
    }
    for (; i < end; i += 4) {
        int s0 = sorted_src[i];
        int s1 = sorted_src[i + 1];
        int s2 = sorted_src[i + 2];
        int s3 = sorted_src[i + 3];
        u32 v0 = h2u[(s0 << 6) + lane];
        u32 v1 = h2u[(s1 << 6) + lane];
        u32 v2 = h2u[(s2 << 6) + lane];
        u32 v3 = h2u[(s3 << 6) + lane];
        a0 += bf_lo(v0); a1 += bf_hi(v0);
        c0 += bf_lo(v1); c1 += bf_hi(v1);
        a0 += bf_lo(v2); a1 += bf_hi(v2);
        c0 += bf_lo(v3); c1 += bf_hi(v3);
    }
    a0 += c0; a1 += c1;

    float2 bb = *(const float2*)(b2 + (lane << 1));
    float2 o;
    o.x = a0 * disd + bb.x;
    o.y = a1 * disd + bb.y;
    *(float2*)(out + ((size_t)tgt << 7) + (lane << 1)) = o;
}

extern "C" void kernel_launch(void* const* d_in, const int* in_sizes, int n_in,
                              void* d_out, int out_size, void* d_ws, size_t ws_size,
                              hipStream_t stream) {
    const int* reg_id = (const int*)d_in[0];
    const int* edge = (const int*)d_in[1];
    const float* W1 = (const float*)d_in[2];
    const float* b1 = (const float*)d_in[3];
    const float* W2 = (const float*)d_in[4];
    const float* b2 = (const float*)d_in[5];
    float* out = (float*)d_out;

    char* ws = (char*)d_ws;
    int* deg = (int*)(ws + OFF_DEG);
    int* row_start = (int*)(ws + OFF_ROWSTART);
    int* cursor = (int*)(ws + OFF_CURSOR);
    float* dis = (float*)(ws + OFF_DIS);
    int* sorted_src = (int*)(ws + OFF_SORTED);
    u32* W1h = (u32*)(ws + OFF_W1H);
    u32* h1s = (u32*)(ws + OFF_H1S);
    u32* w2t = (u32*)(ws + OFF_W2T);
    u16* h2b = (u16*)(ws + OFF_H2B);

    hipMemsetAsync(deg, 0, N_NODE * sizeof(int), stream);

    hist_kernel<<<N_EDGE / 256, 256, 0, stream>>>(edge, deg);
    scan_kernel<<<1, 1024, 0, stream>>>(deg, row_start, cursor, dis);
    prep_kernel<<<5248, 256, 0, stream>>>(edge, cursor, sorted_src, W1, dis, W1h, W2, w2t);
    layer1_phase<<<2048, 256, 0, stream>>>(W1h, b1, row_start, sorted_src, dis, h1s, 0);
    layer1_phase<<<2048, 256, 0, stream>>>(W1h, b1, row_start, sorted_src, dis, h1s, 1);
    gemm_h2<<<1024, 256, 0, stream>>>(h1s, w2t, h2b);
    layer2_small<<<N_REG / 4, 256, 0, stream>>>((const u32*)h2b, reg_id, row_start,
                                                sorted_src, dis, b2, out);
}